// Round 6
// baseline (255.421 us; speedup 1.0000x reference)
//
#include <hip/hip_runtime.h>

// SpatialAttention fp32: B=128, C=3, H=W=256, 8x8 patches, FEAT=192, ENC=16.
// R6 = R4's wave structure with the weight path moved from SMEM to LDS.
//  - 4 waves/block share the same 64 patches (patch = lane -> float4 I/O,
//    zero write amplification); wave w owns features [48w, 48w+48).
//  - Weights staged once per block into LDS (coalesced float4); all hot-loop
//    weight reads are uniform-address ds_read_b128 broadcasts: IN-ORDER
//    return -> fine-grained lgkmcnt pipelining (SMEM's out-of-order return
//    forced lgkmcnt(0) drains = R4's 70% stall; R3's per-lane VMEM = TA storm).
//  - o[48] kept in registers (decoder runs once); exp recomputed at store.
//  - softmax needs no max-subtraction: out = relu(...) bounded ~<=12.

constexpr int NPATCH = 128 * 32 * 32;
constexpr float L2E  = 1.4426950408889634f;

__global__ __launch_bounds__(256, 3) void spatial_attn(
    const float* __restrict__ x,      // [128][3][256][256]
    const float* __restrict__ Wenc,   // [16][192]
    const float* __restrict__ benc,   // [16]
    const float* __restrict__ Wdec,   // [192][16]
    const float* __restrict__ bdec,   // [192]
    float* __restrict__ y)            // [128][3][256][256]
{
  __shared__ float lds[10720];        // 42.9 KB -> 3 blocks/CU
  float* wencS = lds;                 // [16][192] natural layout
  float* wdecS = lds + 3072;          // [192][16] natural layout
  float* bdecS = lds + 6144;          // [192]
  float* bencS = lds + 6336;          // [16]
  float* encl  = lds + 6352;          // [16][257] cross-wave reduce (2-way free)
  float* sls   = lds + 10464;         // [256]

  const int tid  = threadIdx.x;
  const int lane = tid & 63;
  const int wv   = tid >> 6;          // wave id 0..3 (uniform per wave)
  const int p    = blockIdx.x * 64 + lane;      // patch = lane
  const int b    = p >> 10;
  const int ii   = (p >> 5) & 31;
  const int jj   = p & 31;
  const size_t base = (size_t)b * 196608 + (size_t)ii * 2048 + (size_t)jj * 8;

  // ---- x loads first: 12 independent coalesced dwordx4, overlap staging ----
  float xv[48];                       // this wave's 48 features, f-local order
  #pragma unroll
  for (int t = 0; t < 6; ++t) {
    const int cr = 6 * wv + t;
    const float* src = x + base + (cr >> 3) * 65536 + (cr & 7) * 256;
    const float4 v0 = *(const float4*)(src);
    const float4 v1 = *(const float4*)(src + 4);
    xv[t*8+0]=v0.x; xv[t*8+1]=v0.y; xv[t*8+2]=v0.z; xv[t*8+3]=v0.w;
    xv[t*8+4]=v1.x; xv[t*8+5]=v1.y; xv[t*8+6]=v1.z; xv[t*8+7]=v1.w;
  }

  // ---- Stage weights into LDS: 768+768 float4, fully coalesced ----
  {
    const float4* wge = (const float4*)Wenc;
    const float4* wgd = (const float4*)Wdec;
    float4* sle = (float4*)wencS;
    float4* sld = (float4*)wdecS;
    #pragma unroll
    for (int k = 0; k < 3; ++k) {
      sle[tid + 256 * k] = wge[tid + 256 * k];
      sld[tid + 256 * k] = wgd[tid + 256 * k];
    }
    if (tid < 192) bdecS[tid] = bdec[tid];
    if (tid < 16)  bencS[tid] = benc[tid];
  }
  __syncthreads();

  // ---- Encoder partial over this wave's 48 features ----
  float acc[16];
  #pragma unroll
  for (int e = 0; e < 16; ++e) acc[e] = 0.0f;
  const float4* wE = (const float4*)wencS;      // [e][48 float4]
  #pragma unroll 4
  for (int ch = 0; ch < 12; ++ch) {             // 4 features per step
    const float x0 = xv[4*ch], x1 = xv[4*ch+1], x2 = xv[4*ch+2], x3 = xv[4*ch+3];
    #pragma unroll
    for (int e = 0; e < 16; ++e) {
      const float4 w = wE[e * 48 + wv * 12 + ch];   // uniform -> broadcast
      acc[e] = fmaf(w.x, x0, acc[e]);
      acc[e] = fmaf(w.y, x1, acc[e]);
      acc[e] = fmaf(w.z, x2, acc[e]);
      acc[e] = fmaf(w.w, x3, acc[e]);
    }
  }

  // ---- Cross-wave reduce of acc[16] (all LDS patterns 2-way = free) ----
  #pragma unroll
  for (int e = 0; e < 16; ++e) encl[e * 257 + tid] = acc[e];
  __syncthreads();
  #pragma unroll
  for (int e = 0; e < 16; ++e) {
    const float a = encl[e * 257 + lane]       + encl[e * 257 + 64  + lane]
                  + encl[e * 257 + 128 + lane] + encl[e * 257 + 192 + lane];
    acc[e] = fmaxf(a + bencS[e], 0.0f);
  }

  // ---- Decoder: this wave's 48 outputs, kept in registers ----
  const float4* wD = (const float4*)wdecS;      // [f][4 float4]
  float o[48];
  float s = 0.0f;
  #pragma unroll 8
  for (int u = 0; u < 48; ++u) {
    const int fg = wv * 48 + u;
    const float4 w0 = wD[fg * 4 + 0];           // uniform -> broadcast
    const float4 w1 = wD[fg * 4 + 1];
    const float4 w2 = wD[fg * 4 + 2];
    const float4 w3 = wD[fg * 4 + 3];
    float v = bdecS[fg];
    v = fmaf(w0.x, acc[0],  v); v = fmaf(w0.y, acc[1],  v);
    v = fmaf(w0.z, acc[2],  v); v = fmaf(w0.w, acc[3],  v);
    v = fmaf(w1.x, acc[4],  v); v = fmaf(w1.y, acc[5],  v);
    v = fmaf(w1.z, acc[6],  v); v = fmaf(w1.w, acc[7],  v);
    v = fmaf(w2.x, acc[8],  v); v = fmaf(w2.y, acc[9],  v);
    v = fmaf(w2.z, acc[10], v); v = fmaf(w2.w, acc[11], v);
    v = fmaf(w3.x, acc[12], v); v = fmaf(w3.y, acc[13], v);
    v = fmaf(w3.z, acc[14], v); v = fmaf(w3.w, acc[15], v);
    v = fmaxf(v, 0.0f);
    o[u] = v;
    s += __builtin_amdgcn_exp2f(v * L2E);
  }

  // ---- Softmax denominator across the 4 waves ----
  sls[tid] = s;
  __syncthreads();
  const float st = sls[lane] + sls[lane + 64] + sls[lane + 128] + sls[lane + 192];
  const float inv = __builtin_amdgcn_rcpf(st);

  // ---- y = softmax(out)*out, coalesced float4 stores ----
  #pragma unroll
  for (int t = 0; t < 6; ++t) {
    const int cr = 6 * wv + t;
    float* dst = y + base + (cr >> 3) * 65536 + (cr & 7) * 256;
    float r[8];
    #pragma unroll
    for (int c = 0; c < 8; ++c) {
      const float ov = o[t * 8 + c];
      r[c] = __builtin_amdgcn_exp2f(ov * L2E) * inv * ov;
    }
    const float4 s0 = {r[0], r[1], r[2], r[3]};
    const float4 s1 = {r[4], r[5], r[6], r[7]};
    *(float4*)(dst)     = s0;
    *(float4*)(dst + 4) = s1;
  }
}

extern "C" void kernel_launch(void* const* d_in, const int* in_sizes, int n_in,
                              void* d_out, int out_size, void* d_ws, size_t ws_size,
                              hipStream_t stream) {
  const float* x    = (const float*)d_in[0];
  const float* Wenc = (const float*)d_in[1];
  const float* benc = (const float*)d_in[2];
  const float* Wdec = (const float*)d_in[3];
  const float* bdec = (const float*)d_in[4];
  float* y = (float*)d_out;
  dim3 grid(NPATCH / 64), block(256);
  hipLaunchKernelGGL(spatial_attn, grid, block, 0, stream, x, Wenc, benc, Wdec, bdec, y);
}